// Round 13
// baseline (320.960 us; speedup 1.0000x reference)
//
#include <hip/hip_runtime.h>
#include <hip/hip_bf16.h>

// Problem constants
constexpr int Bb  = 8;
constexpr int Ss  = 2048;
constexpr int Ee  = 128;
constexpr int Hh  = 8;
constexpr int HSs = 16;
constexpr int QKVSZ = Bb * Hh * Ss * HSs;  // 2,097,152 elements per tensor

typedef _Float16 f16;
typedef __attribute__((ext_vector_type(8)))  _Float16 f16x8;   // 8 f16 = 4 VGPRs
typedef __attribute__((ext_vector_type(16))) float f32x16;

constexpr float QSCALE = 5.770780163555854f;  // 4 * log2(e); folded into stored k

// RTZ packed fp32x2 -> fp16x2
__device__ __forceinline__ unsigned pack_rtz(float lo, float hi) {
    union { __fp16 __attribute__((ext_vector_type(2))) h; unsigned u; } c;
    c.h = __builtin_amdgcn_cvt_pkrtz(lo, hi);
    return c.u;
}
// RNE pair pack
__device__ __forceinline__ unsigned pack_rne(float lo, float hi) {
    union { __attribute__((ext_vector_type(2))) _Float16 h; unsigned u; } c;
    c.h[0] = (f16)lo; c.h[1] = (f16)hi;
    return c.u;
}

// ---------------------------------------------------------------------------
// prep: (a) fp32->f16 of all weights into wh=[wq|wk|wv|wp];
//       (b) constant pad rows of the frag-ordered V buffer (m=16 row -> 1.0
//           for the MFMA-l trick, m=17..31 -> 0), fully coalesced.
// ---------------------------------------------------------------------------
__global__ __launch_bounds__(256) void prep_kernel(
    const float* __restrict__ Wq, const float* __restrict__ Wk,
    const float* __restrict__ Wv, const float* __restrict__ Wp,
    f16* __restrict__ wh, f16* __restrict__ vo)
{
    const int idx = blockIdx.x * 256 + threadIdx.x;
    if (idx < 16384) {
        const int i = idx * 4;
        const float* src = (i < 16384) ? (Wq + i)
                         : (i < 32768) ? (Wk + i - 16384)
                         : (i < 49152) ? (Wv + i - 32768) : (Wp + i - 49152);
        float4 v = *(const float4*)src;
        union { f16 h[4]; uint2 u; } c;
        c.h[0] = (f16)v.x; c.h[1] = (f16)v.y; c.h[2] = (f16)v.z; c.h[3] = (f16)v.w;
        *(uint2*)(wh + i) = c.u;
    } else {
        const int p = idx - 16384;                 // 0..262143 pad chunks (16B)
        const int lane32 = p & 31, g = (p >> 5) & 3, it = (p >> 7) & 31, bh = p >> 12;
        const int lanep = 16 + (lane32 & 15) + (lane32 >> 4) * 32;  // 16..31, 48..63
        const unsigned one2 = 0x3C003C00u;
        uint4 val = ((lane32 & 15) == 0) ? (uint4){one2, one2, one2, one2}
                                         : (uint4){0, 0, 0, 0};
        *(uint4*)(vo + (size_t)bh * 65536 + it * 2048 + g * 512 + lanep * 8) = val;
    }
}

// ---------------------------------------------------------------------------
// Kernel A: Q/K/V projection, all 3 mats fused (X staged once). Grid 512 x
// 256 thr. A-frags from LDS; W f16 (L1-hot). v acc routed through an LDS
// transpose -> coalesced uint4 frag-order stores (data rows only; pads are
// pre-written by prep). q/k direct stores, k scaled by QSCALE.
// V frag-order: elem (s,d) -> bh*65536 + (s>>6)*2048 + ((s>>4)&3)*512
//                             + (d + 32*((s>>3)&1))*8 + (s&7)
// 32x32x16 layouts: A[m=lane&31][k=8h+j], B[k=8h+j][n=lane&31],
// C/D[row=(r&3)+8(r>>2)+4h][col=lane&31].
// ---------------------------------------------------------------------------
__global__ __launch_bounds__(256) void qkv_kernel(
    const float* __restrict__ x, const f16* __restrict__ wh,
    f16* __restrict__ qo, f16* __restrict__ ko, f16* __restrict__ vo)
{
    constexpr int LDW = 136;                      // padded row (f16), b128-aligned
    __shared__ __align__(16) f16 Xs[32 * LDW];    // 8.7 KB, reused for v transpose

    const int rowbase = blockIdx.x * 32;

    // stage X tile (32 x 128) fp32 -> f16, coalesced float4 reads
    for (int idx = threadIdx.x; idx < 32 * 32; idx += 256) {
        const int r = idx >> 5, cp = idx & 31;
        float4 v = *(const float4*)(x + (size_t)(rowbase + r) * Ee + cp * 4);
        union { f16 h[4]; uint2 u; } c;
        c.h[0] = (f16)v.x; c.h[1] = (f16)v.y; c.h[2] = (f16)v.z; c.h[3] = (f16)v.w;
        *(uint2*)&Xs[r * LDW + cp * 4] = c.u;
    }
    __syncthreads();

    const int wv_ = threadIdx.x >> 6, lane = threadIdx.x & 63;
    const int h = lane >> 5, n31 = lane & 31;

    f16x8 A[8];
#pragma unroll
    for (int t = 0; t < 8; ++t)
        A[t] = *(const f16x8*)&Xs[n31 * LDW + 16 * t + 8 * h];
    __syncthreads();                              // all A-frag reads done

    const int c = wv_ * 32 + n31;                 // channel 0..127 = head*16+d
    const int b = rowbase >> 11;
    const int s0 = rowbase & 2047;
    const int head = c >> 4, d = c & 15;
    const int bh = b * Hh + head;

    // --- V first: MFMA then transpose via Xs ---
    {
        const f16* wr = wh + 2 * 16384 + (size_t)c * Ee + 8 * h;
        f32x16 acc = {};
#pragma unroll
        for (int t = 0; t < 8; ++t)
            acc = __builtin_amdgcn_mfma_f32_32x32x16_f16(A[t], *(const f16x8*)(wr + 16 * t), acc, 0, 0, 0);
#pragma unroll
        for (int r = 0; r < 16; ++r) {
            const int row = (r & 3) + 8 * (r >> 2) + 4 * h;
            Xs[row * LDW + c] = (f16)acc[r];
        }
    }

    // --- Q and K while the transpose settles ---
#pragma unroll
    for (int mat = 0; mat < 2; ++mat) {
        const f16* wr = wh + mat * 16384 + (size_t)c * Ee + 8 * h;
        f32x16 acc = {};
#pragma unroll
        for (int t = 0; t < 8; ++t)
            acc = __builtin_amdgcn_mfma_f32_32x32x16_f16(A[t], *(const f16x8*)(wr + 16 * t), acc, 0, 0, 0);
        f16* dst = (mat == 0) ? qo : ko;
        const float scale = (mat == 1) ? QSCALE : 1.f;
#pragma unroll
        for (int r = 0; r < 16; ++r) {
            const int s = s0 + (r & 3) + 8 * (r >> 2) + 4 * h;
            dst[((size_t)bh * Ss + s) * HSs + d] = (f16)(acc[r] * scale);
        }
    }
    __syncthreads();                              // v transpose complete

    // coalesced frag-order v stores (512 uint4 per block, data rows only)
    const int it = s0 >> 6, g0 = (s0 >> 4) & 3;
    for (int p = threadIdx.x; p < 512; p += 256) {
        const int gl = p >> 8, hd = (p >> 5) & 7, dd = (p >> 1) & 15, eh = p & 1;
        union { f16 hv[8]; uint4 u; } pkt;
#pragma unroll
        for (int j = 0; j < 8; ++j)
            pkt.hv[j] = Xs[(gl * 16 + eh * 8 + j) * LDW + hd * 16 + dd];
        *(uint4*)(vo + (size_t)(b * Hh + hd) * 65536 + it * 2048
                  + (g0 + gl) * 512 + (dd + 32 * eh) * 8) = pkt.u;
    }
}

// ---------------------------------------------------------------------------
// Kernel B: MFMA flash attention, split-K across 2 waves per block.
// 4096 blocks x 128 thr (16 wg/CU -> up to 32 waves/CU). Wave w streams keys
// [w*1024, (w+1)*1024) over its 32 queries; ends with an LDS merge of
// (m, l, O) and wave 0 writes the normalized f16 output. No LDS in the main
// loop; all MFMA operands direct 16B/lane global loads (V pre-swizzled,
// ones-row for l in acc[8]). XCD swizzle: bh groups pinned per XCD.
// ---------------------------------------------------------------------------
__device__ __forceinline__ void cb_exchange(const unsigned* pw, int h,
                                            f16x8& Blo, f16x8& Bhi) {
    unsigned exa = (unsigned)__shfl_xor((int)(h ? pw[0] : pw[2]), 32, 64);
    unsigned exb = (unsigned)__shfl_xor((int)(h ? pw[1] : pw[3]), 32, 64);
    unsigned exc = (unsigned)__shfl_xor((int)(h ? pw[4] : pw[6]), 32, 64);
    unsigned exd = (unsigned)__shfl_xor((int)(h ? pw[5] : pw[7]), 32, 64);
    union { unsigned u[4]; f16x8 v; } B1, B2;
    if (h == 0) {
        B1.u[0] = pw[0]; B1.u[1] = pw[1]; B1.u[2] = exa; B1.u[3] = exb;
        B2.u[0] = pw[4]; B2.u[1] = pw[5]; B2.u[2] = exc; B2.u[3] = exd;
    } else {
        B1.u[0] = exa; B1.u[1] = exb; B1.u[2] = pw[2]; B1.u[3] = pw[3];
        B2.u[0] = exc; B2.u[1] = exd; B2.u[2] = pw[6]; B2.u[3] = pw[7];
    }
    Blo = B1.v; Bhi = B2.v;
}

__global__ __launch_bounds__(128, 6) void attn_kernel(
    const f16* __restrict__ qg, const f16* __restrict__ kg,
    const f16* __restrict__ vg, f16* __restrict__ og)
{
    __shared__ float cmb[32 * 20];                 // [q][d0..15, l, m], 2.5 KB

    const int blk  = blockIdx.x;                   // 4096
    const int bh   = (blk & 7) * 8 + (blk >> 9);   // XCD-local bh groups
    const int qblk = (blk >> 3) & 63;
    const int wv_  = threadIdx.x >> 6;             // key-half owner
    const int lane = threadIdx.x & 63;
    const int h    = lane >> 5;
    const int q31  = lane & 31;
    const int qbase = qblk * 32;

    // Q B-frag (QSCALE folded into k); same for both waves
    const f16x8 qf = *(const f16x8*)(qg + ((size_t)bh * Ss + qbase + q31) * HSs + 8 * h);

    // per-lane streaming pointers, offset by this wave's key half
    const f16* pk = kg + (size_t)bh * Ss * HSs + wv_ * 1024 * HSs + q31 * 16 + 8 * h;
    const f16* pv = vg + (size_t)bh * 65536 + wv_ * 32768 + lane * 8;

    f16x8 ka0 = *(const f16x8*)pk;
    f16x8 ka1 = *(const f16x8*)(pk + 512);
    f16x8 va0 = *(const f16x8*)(pv);
    f16x8 va1 = *(const f16x8*)(pv + 512);
    f16x8 va2 = *(const f16x8*)(pv + 1024);
    f16x8 va3 = *(const f16x8*)(pv + 1536);

    f32x16 acc = {};
    const f32x16 z16 = {};
    float m = -1e30f;

    for (int it = 0; it < 16; ++it) {              // 16 chunks of 64 keys
        f16x8 nk0, nk1, nv0, nv1, nv2, nv3;
        if (it < 15) {
            pk += 1024; pv += 2048;
            nk0 = *(const f16x8*)pk;
            nk1 = *(const f16x8*)(pk + 512);
            nv0 = *(const f16x8*)(pv);
            nv1 = *(const f16x8*)(pv + 512);
            nv2 = *(const f16x8*)(pv + 1024);
            nv3 = *(const f16x8*)(pv + 1536);
        }

        f32x16 st0 = __builtin_amdgcn_mfma_f32_32x32x16_f16(ka0, qf, z16, 0, 0, 0);
        f32x16 st1 = __builtin_amdgcn_mfma_f32_32x32x16_f16(ka1, qf, z16, 0, 0, 0);

        // balanced max tree over 32 in-lane values + one xor32
        float t0[8];
#pragma unroll
        for (int t = 0; t < 8; ++t)
            t0[t] = fmaxf(fmaxf(st0[t], st0[t + 8]), fmaxf(st1[t], st1[t + 8]));
#pragma unroll
        for (int t = 0; t < 4; ++t) t0[t] = fmaxf(t0[t], t0[t + 4]);
        float mx = fmaxf(fmaxf(t0[0], t0[1]), fmaxf(t0[2], t0[3]));
        mx = fmaxf(mx, __shfl_xor(mx, 32, 64));
        const float mnew = fmaxf(m, mx);
        const float corr = __builtin_amdgcn_exp2f(m - mnew);
#pragma unroll
        for (int r = 0; r < 9; ++r) acc[r] *= corr;   // d<16 regs + l in acc[8]
        m = mnew;

#pragma unroll
        for (int t = 0; t < 16; ++t) st0[t] = __builtin_amdgcn_exp2f(st0[t] - mnew);
#pragma unroll
        for (int t = 0; t < 16; ++t) st1[t] = __builtin_amdgcn_exp2f(st1[t] - mnew);
        unsigned pw0[8], pw1[8];
#pragma unroll
        for (int r = 0; r < 8; ++r) pw0[r] = pack_rtz(st0[2 * r], st0[2 * r + 1]);
#pragma unroll
        for (int r = 0; r < 8; ++r) pw1[r] = pack_rtz(st1[2 * r], st1[2 * r + 1]);
        f16x8 B1, B2, B3, B4;
        cb_exchange(pw0, h, B1, B2);
        cb_exchange(pw1, h, B3, B4);

        acc = __builtin_amdgcn_mfma_f32_32x32x16_f16(va0, B1, acc, 0, 0, 0);
        acc = __builtin_amdgcn_mfma_f32_32x32x16_f16(va1, B2, acc, 0, 0, 0);
        acc = __builtin_amdgcn_mfma_f32_32x32x16_f16(va2, B3, acc, 0, 0, 0);
        acc = __builtin_amdgcn_mfma_f32_32x32x16_f16(va3, B4, acc, 0, 0, 0);

        ka0 = nk0; ka1 = nk1;
        va0 = nv0; va1 = nv1; va2 = nv2; va3 = nv3;
    }

    // per-lane l for this half (ones-row sits in acc[8] of the h=0 half)
    const float lp = acc[8] + __shfl_xor(acc[8], 32, 64);

    // wave 1 publishes partials; wave 0 merges and writes
    if (wv_ == 1) {
        float* base = &cmb[q31 * 20];
#pragma unroll
        for (int j = 0; j < 4; ++j) { base[4 * h + j] = acc[j]; base[8 + 4 * h + j] = acc[4 + j]; }
        base[16] = lp; base[17] = m;               // both h lanes write same value
    }
    __syncthreads();
    if (wv_ == 0) {
        const float* base = &cmb[q31 * 20];
        const float l2 = base[16], m2 = base[17];
        const float M  = fmaxf(m, m2);
        const float c1 = __builtin_amdgcn_exp2f(m - M);
        const float c2 = __builtin_amdgcn_exp2f(m2 - M);
        const float l  = lp * c1 + l2 * c2;
        const float inv = 1.f / l;
        float o[8];
#pragma unroll
        for (int j = 0; j < 4; ++j) {
            o[j]     = (acc[j]     * c1 + base[4 * h + j]     * c2) * inv;
            o[4 + j] = (acc[4 + j] * c1 + base[8 + 4 * h + j] * c2) * inv;
        }
        const int b = bh >> 3, head = bh & 7;
        f16* op = og + ((size_t)b * Ss + qbase + q31) * Ee + head * HSs;
        uint2 lo = { pack_rne(o[0], o[1]), pack_rne(o[2], o[3]) };
        uint2 hi = { pack_rne(o[4], o[5]), pack_rne(o[6], o[7]) };
        *(uint2*)(op + 4 * h)     = lo;
        *(uint2*)(op + 8 + 4 * h) = hi;
    }
}

// ---------------------------------------------------------------------------
// Kernel C: output projection. 32-row tiles, grid 512, 4 waves (one channel
// group each). O tile staged via LDS coalesced; Wp f16 (L1-hot); fp32 out.
// ---------------------------------------------------------------------------
__global__ __launch_bounds__(256) void proj_kernel(
    const f16* __restrict__ oh, const f16* __restrict__ wph,
    const float* __restrict__ bp, float* __restrict__ out)
{
    constexpr int LDW = 136;
    __shared__ __align__(16) f16 Os[32 * LDW];    // 8.7 KB
    const int rowbase = blockIdx.x * 32;

    for (int idx = threadIdx.x; idx < 512; idx += 256) {
        const int r = idx >> 4, cp = idx & 15;
        *(f16x8*)&Os[r * LDW + cp * 8] =
            *(const f16x8*)(oh + (size_t)(rowbase + r) * Ee + cp * 8);
    }
    __syncthreads();

    const int wv_ = threadIdx.x >> 6, lane = threadIdx.x & 63;
    const int h = lane >> 5, n31 = lane & 31;

    f16x8 A[8];
#pragma unroll
    for (int t = 0; t < 8; ++t)
        A[t] = *(const f16x8*)&Os[n31 * LDW + 16 * t + 8 * h];

    const int e = wv_ * 32 + n31;
    const f16* wr = wph + (size_t)e * Ee + 8 * h;
    f32x16 acc = {};
#pragma unroll
    for (int t = 0; t < 8; ++t)
        acc = __builtin_amdgcn_mfma_f32_32x32x16_f16(A[t], *(const f16x8*)(wr + 16 * t), acc, 0, 0, 0);

    const float bias = bp[e];
#pragma unroll
    for (int r = 0; r < 16; ++r) {
        const int R = rowbase + (r & 3) + 8 * (r >> 2) + 4 * h;
        out[(size_t)R * Ee + e] = acc[r] + bias;
    }
}

// ---------------------------------------------------------------------------
extern "C" void kernel_launch(void* const* d_in, const int* in_sizes, int n_in,
                              void* d_out, int out_size, void* d_ws, size_t ws_size,
                              hipStream_t stream)
{
    const float* x  = (const float*)d_in[0];
    const float* Wk = (const float*)d_in[1];
    const float* Wq = (const float*)d_in[2];
    const float* Wv = (const float*)d_in[3];
    const float* Wp = (const float*)d_in[4];
    const float* bp = (const float*)d_in[5];
    float* out = (float*)d_out;

    f16* ws = (f16*)d_ws;
    f16* qh = ws;                            // 2M halves
    f16* kh = ws + (size_t)QKVSZ;            // 2M
    f16* vh = ws + (size_t)2 * QKVSZ;        // 4M (A-frag order + pad rows)
    f16* oh = ws + (size_t)4 * QKVSZ;        // 2M
    f16* wh = ws + (size_t)5 * QKVSZ;        // 64K: wq|wk|wv|wp

    prep_kernel<<<1088, 256, 0, stream>>>(Wq, Wk, Wv, Wp, wh, vh);
    qkv_kernel<<<Bb * Ss / 32, 256, 0, stream>>>(x, wh, qh, kh, vh);
    attn_kernel<<<Bb * Hh * (Ss / 32), 128, 0, stream>>>(qh, kh, vh, oh);
    proj_kernel<<<Bb * Ss / 32, 256, 0, stream>>>(oh, wh + 49152, bp, out);
}

// Round 14
// 142.276 us; speedup vs baseline: 2.2559x; 2.2559x over previous
//
#include <hip/hip_runtime.h>
#include <hip/hip_bf16.h>

// Problem constants
constexpr int Bb  = 8;
constexpr int Ss  = 2048;
constexpr int Ee  = 128;
constexpr int Hh  = 8;
constexpr int HSs = 16;
constexpr int QKVSZ = Bb * Hh * Ss * HSs;  // 2,097,152 elements per tensor

typedef _Float16 f16;
typedef __attribute__((ext_vector_type(8)))  _Float16 f16x8;   // 8 f16 = 4 VGPRs
typedef __attribute__((ext_vector_type(16))) float f32x16;

constexpr float QSCALE = 5.770780163555854f;  // 4 * log2(e); folded into stored k

// RTZ packed fp32x2 -> fp16x2
__device__ __forceinline__ unsigned pack_rtz(float lo, float hi) {
    union { __fp16 __attribute__((ext_vector_type(2))) h; unsigned u; } c;
    c.h = __builtin_amdgcn_cvt_pkrtz(lo, hi);
    return c.u;
}
// RNE pair pack
__device__ __forceinline__ unsigned pack_rne(float lo, float hi) {
    union { __attribute__((ext_vector_type(2))) _Float16 h; unsigned u; } c;
    c.h[0] = (f16)lo; c.h[1] = (f16)hi;
    return c.u;
}

// ---------------------------------------------------------------------------
// prep: (a) fp32->f16 of all weights into wh=[wq|wk|wv|wp];
//       (b) constant pad rows of the frag-ordered V buffer (m=16 row -> 1.0
//           for the MFMA-l trick, m=17..31 -> 0), fully coalesced.
// ---------------------------------------------------------------------------
__global__ __launch_bounds__(256) void prep_kernel(
    const float* __restrict__ Wq, const float* __restrict__ Wk,
    const float* __restrict__ Wv, const float* __restrict__ Wp,
    f16* __restrict__ wh, f16* __restrict__ vo)
{
    const int idx = blockIdx.x * 256 + threadIdx.x;
    if (idx < 16384) {
        const int i = idx * 4;
        const float* src = (i < 16384) ? (Wq + i)
                         : (i < 32768) ? (Wk + i - 16384)
                         : (i < 49152) ? (Wv + i - 32768) : (Wp + i - 49152);
        float4 v = *(const float4*)src;
        union { f16 h[4]; uint2 u; } c;
        c.h[0] = (f16)v.x; c.h[1] = (f16)v.y; c.h[2] = (f16)v.z; c.h[3] = (f16)v.w;
        *(uint2*)(wh + i) = c.u;
    } else {
        const int p = idx - 16384;                 // 0..262143 pad chunks (16B)
        const int lane32 = p & 31, g = (p >> 5) & 3, it = (p >> 7) & 31, bh = p >> 12;
        const int lanep = 16 + (lane32 & 15) + (lane32 >> 4) * 32;  // 16..31, 48..63
        const unsigned one2 = 0x3C003C00u;
        uint4 val = ((lane32 & 15) == 0) ? (uint4){one2, one2, one2, one2}
                                         : (uint4){0, 0, 0, 0};
        *(uint4*)(vo + (size_t)bh * 65536 + it * 2048 + g * 512 + lanep * 8) = val;
    }
}

// ---------------------------------------------------------------------------
// Kernel A: Q/K/V projection, all 3 mats fused (X staged once). Grid 512 x
// 256 thr. A-frags from LDS; W f16 (L1-hot). v acc routed through an LDS
// transpose -> coalesced uint4 frag-order stores (data rows only; pads are
// pre-written by prep). q/k direct stores, k scaled by QSCALE.
// V frag-order: elem (s,d) -> bh*65536 + (s>>6)*2048 + ((s>>4)&3)*512
//                             + (d + 32*((s>>3)&1))*8 + (s&7)
// 32x32x16 layouts: A[m=lane&31][k=8h+j], B[k=8h+j][n=lane&31],
// C/D[row=(r&3)+8(r>>2)+4h][col=lane&31].
// ---------------------------------------------------------------------------
__global__ __launch_bounds__(256) void qkv_kernel(
    const float* __restrict__ x, const f16* __restrict__ wh,
    f16* __restrict__ qo, f16* __restrict__ ko, f16* __restrict__ vo)
{
    constexpr int LDW = 136;                      // padded row (f16), b128-aligned
    __shared__ __align__(16) f16 Xs[32 * LDW];    // 8.7 KB, reused for v transpose

    const int rowbase = blockIdx.x * 32;

    // stage X tile (32 x 128) fp32 -> f16, coalesced float4 reads
    for (int idx = threadIdx.x; idx < 32 * 32; idx += 256) {
        const int r = idx >> 5, cp = idx & 31;
        float4 v = *(const float4*)(x + (size_t)(rowbase + r) * Ee + cp * 4);
        union { f16 h[4]; uint2 u; } c;
        c.h[0] = (f16)v.x; c.h[1] = (f16)v.y; c.h[2] = (f16)v.z; c.h[3] = (f16)v.w;
        *(uint2*)&Xs[r * LDW + cp * 4] = c.u;
    }
    __syncthreads();

    const int wv_ = threadIdx.x >> 6, lane = threadIdx.x & 63;
    const int h = lane >> 5, n31 = lane & 31;

    f16x8 A[8];
#pragma unroll
    for (int t = 0; t < 8; ++t)
        A[t] = *(const f16x8*)&Xs[n31 * LDW + 16 * t + 8 * h];
    __syncthreads();                              // all A-frag reads done

    const int c = wv_ * 32 + n31;                 // channel 0..127 = head*16+d
    const int b = rowbase >> 11;
    const int s0 = rowbase & 2047;
    const int head = c >> 4, d = c & 15;
    const int bh = b * Hh + head;

    // --- V first: MFMA then transpose via Xs ---
    {
        const f16* wr = wh + 2 * 16384 + (size_t)c * Ee + 8 * h;
        f32x16 acc = {};
#pragma unroll
        for (int t = 0; t < 8; ++t)
            acc = __builtin_amdgcn_mfma_f32_32x32x16_f16(A[t], *(const f16x8*)(wr + 16 * t), acc, 0, 0, 0);
#pragma unroll
        for (int r = 0; r < 16; ++r) {
            const int row = (r & 3) + 8 * (r >> 2) + 4 * h;
            Xs[row * LDW + c] = (f16)acc[r];
        }
    }

    // --- Q and K while the transpose settles ---
#pragma unroll
    for (int mat = 0; mat < 2; ++mat) {
        const f16* wr = wh + mat * 16384 + (size_t)c * Ee + 8 * h;
        f32x16 acc = {};
#pragma unroll
        for (int t = 0; t < 8; ++t)
            acc = __builtin_amdgcn_mfma_f32_32x32x16_f16(A[t], *(const f16x8*)(wr + 16 * t), acc, 0, 0, 0);
        f16* dst = (mat == 0) ? qo : ko;
        const float scale = (mat == 1) ? QSCALE : 1.f;
#pragma unroll
        for (int r = 0; r < 16; ++r) {
            const int s = s0 + (r & 3) + 8 * (r >> 2) + 4 * h;
            dst[((size_t)bh * Ss + s) * HSs + d] = (f16)(acc[r] * scale);
        }
    }
    __syncthreads();                              // v transpose complete

    // coalesced frag-order v stores (512 uint4 per block, data rows only)
    const int it = s0 >> 6, g0 = (s0 >> 4) & 3;
    for (int p = threadIdx.x; p < 512; p += 256) {
        const int gl = p >> 8, hd = (p >> 5) & 7, dd = (p >> 1) & 15, eh = p & 1;
        union { f16 hv[8]; uint4 u; } pkt;
#pragma unroll
        for (int j = 0; j < 8; ++j)
            pkt.hv[j] = Xs[(gl * 16 + eh * 8 + j) * LDW + hd * 16 + dd];
        *(uint4*)(vo + (size_t)(b * Hh + hd) * 65536 + it * 2048
                  + (g0 + gl) * 512 + (dd + 32 * eh) * 8) = pkt.u;
    }
}

// ---------------------------------------------------------------------------
// Kernel B: MFMA flash attention, split-K across 2 waves per block.
// 4096 blocks x 128 thr. Wave w streams keys [w*1024, (w+1)*1024) over its
// 32 queries; LDS merge of (m, l, O) at the end; wave 0 writes f16 output.
// No LDS in main loop; all MFMA operands direct 16B/lane global loads
// (V pre-swizzled, ones-row for l in acc[8]). XCD swizzle pins bh per XCD.
// __launch_bounds__(128, 3): VGPR cap ~170 >> ~64 needed — NO SPILL
// (R13's (128,6) capped at 40 VGPR and spilled 718 MB of scratch).
// ---------------------------------------------------------------------------
__device__ __forceinline__ void cb_exchange(const unsigned* pw, int h,
                                            f16x8& Blo, f16x8& Bhi) {
    unsigned exa = (unsigned)__shfl_xor((int)(h ? pw[0] : pw[2]), 32, 64);
    unsigned exb = (unsigned)__shfl_xor((int)(h ? pw[1] : pw[3]), 32, 64);
    unsigned exc = (unsigned)__shfl_xor((int)(h ? pw[4] : pw[6]), 32, 64);
    unsigned exd = (unsigned)__shfl_xor((int)(h ? pw[5] : pw[7]), 32, 64);
    union { unsigned u[4]; f16x8 v; } B1, B2;
    if (h == 0) {
        B1.u[0] = pw[0]; B1.u[1] = pw[1]; B1.u[2] = exa; B1.u[3] = exb;
        B2.u[0] = pw[4]; B2.u[1] = pw[5]; B2.u[2] = exc; B2.u[3] = exd;
    } else {
        B1.u[0] = exa; B1.u[1] = exb; B1.u[2] = pw[2]; B1.u[3] = pw[3];
        B2.u[0] = exc; B2.u[1] = exd; B2.u[2] = pw[6]; B2.u[3] = pw[7];
    }
    Blo = B1.v; Bhi = B2.v;
}

__global__ __launch_bounds__(128, 3) void attn_kernel(
    const f16* __restrict__ qg, const f16* __restrict__ kg,
    const f16* __restrict__ vg, f16* __restrict__ og)
{
    __shared__ float cmb[32 * 20];                 // [q][d0..15, l, m], 2.5 KB

    const int blk  = blockIdx.x;                   // 4096
    const int bh   = (blk & 7) * 8 + (blk >> 9);   // XCD-local bh groups
    const int qblk = (blk >> 3) & 63;
    const int wv_  = threadIdx.x >> 6;             // key-half owner
    const int lane = threadIdx.x & 63;
    const int h    = lane >> 5;
    const int q31  = lane & 31;
    const int qbase = qblk * 32;

    // Q B-frag (QSCALE folded into k); same for both waves
    const f16x8 qf = *(const f16x8*)(qg + ((size_t)bh * Ss + qbase + q31) * HSs + 8 * h);

    // per-lane streaming pointers, offset by this wave's key half
    const f16* pk = kg + (size_t)bh * Ss * HSs + wv_ * 1024 * HSs + q31 * 16 + 8 * h;
    const f16* pv = vg + (size_t)bh * 65536 + wv_ * 32768 + lane * 8;

    f16x8 ka0 = *(const f16x8*)pk;
    f16x8 ka1 = *(const f16x8*)(pk + 512);
    f16x8 va0 = *(const f16x8*)(pv);
    f16x8 va1 = *(const f16x8*)(pv + 512);
    f16x8 va2 = *(const f16x8*)(pv + 1024);
    f16x8 va3 = *(const f16x8*)(pv + 1536);

    f32x16 acc = {};
    const f32x16 z16 = {};
    float m = -1e30f;

    for (int it = 0; it < 16; ++it) {              // 16 chunks of 64 keys
        f16x8 nk0, nk1, nv0, nv1, nv2, nv3;
        if (it < 15) {
            pk += 1024; pv += 2048;
            nk0 = *(const f16x8*)pk;
            nk1 = *(const f16x8*)(pk + 512);
            nv0 = *(const f16x8*)(pv);
            nv1 = *(const f16x8*)(pv + 512);
            nv2 = *(const f16x8*)(pv + 1024);
            nv3 = *(const f16x8*)(pv + 1536);
        }

        f32x16 st0 = __builtin_amdgcn_mfma_f32_32x32x16_f16(ka0, qf, z16, 0, 0, 0);
        f32x16 st1 = __builtin_amdgcn_mfma_f32_32x32x16_f16(ka1, qf, z16, 0, 0, 0);

        // balanced max tree over 32 in-lane values + one xor32
        float t0[8];
#pragma unroll
        for (int t = 0; t < 8; ++t)
            t0[t] = fmaxf(fmaxf(st0[t], st0[t + 8]), fmaxf(st1[t], st1[t + 8]));
#pragma unroll
        for (int t = 0; t < 4; ++t) t0[t] = fmaxf(t0[t], t0[t + 4]);
        float mx = fmaxf(fmaxf(t0[0], t0[1]), fmaxf(t0[2], t0[3]));
        mx = fmaxf(mx, __shfl_xor(mx, 32, 64));
        const float mnew = fmaxf(m, mx);
        const float corr = __builtin_amdgcn_exp2f(m - mnew);
#pragma unroll
        for (int r = 0; r < 9; ++r) acc[r] *= corr;   // d<16 regs + l in acc[8]
        m = mnew;

#pragma unroll
        for (int t = 0; t < 16; ++t) st0[t] = __builtin_amdgcn_exp2f(st0[t] - mnew);
#pragma unroll
        for (int t = 0; t < 16; ++t) st1[t] = __builtin_amdgcn_exp2f(st1[t] - mnew);
        unsigned pw0[8], pw1[8];
#pragma unroll
        for (int r = 0; r < 8; ++r) pw0[r] = pack_rtz(st0[2 * r], st0[2 * r + 1]);
#pragma unroll
        for (int r = 0; r < 8; ++r) pw1[r] = pack_rtz(st1[2 * r], st1[2 * r + 1]);
        f16x8 B1, B2, B3, B4;
        cb_exchange(pw0, h, B1, B2);
        cb_exchange(pw1, h, B3, B4);

        acc = __builtin_amdgcn_mfma_f32_32x32x16_f16(va0, B1, acc, 0, 0, 0);
        acc = __builtin_amdgcn_mfma_f32_32x32x16_f16(va1, B2, acc, 0, 0, 0);
        acc = __builtin_amdgcn_mfma_f32_32x32x16_f16(va2, B3, acc, 0, 0, 0);
        acc = __builtin_amdgcn_mfma_f32_32x32x16_f16(va3, B4, acc, 0, 0, 0);

        ka0 = nk0; ka1 = nk1;
        va0 = nv0; va1 = nv1; va2 = nv2; va3 = nv3;
    }

    // per-lane l for this half (ones-row sits in acc[8] of the h=0 half)
    const float lp = acc[8] + __shfl_xor(acc[8], 32, 64);

    // wave 1 publishes partials; wave 0 merges and writes
    if (wv_ == 1) {
        float* base = &cmb[q31 * 20];
#pragma unroll
        for (int j = 0; j < 4; ++j) { base[4 * h + j] = acc[j]; base[8 + 4 * h + j] = acc[4 + j]; }
        base[16] = lp; base[17] = m;               // both h lanes write same value
    }
    __syncthreads();
    if (wv_ == 0) {
        const float* base = &cmb[q31 * 20];
        const float l2 = base[16], m2 = base[17];
        const float M  = fmaxf(m, m2);
        const float c1 = __builtin_amdgcn_exp2f(m - M);
        const float c2 = __builtin_amdgcn_exp2f(m2 - M);
        const float l  = lp * c1 + l2 * c2;
        const float inv = 1.f / l;
        float o[8];
#pragma unroll
        for (int j = 0; j < 4; ++j) {
            o[j]     = (acc[j]     * c1 + base[4 * h + j]     * c2) * inv;
            o[4 + j] = (acc[4 + j] * c1 + base[8 + 4 * h + j] * c2) * inv;
        }
        const int b = bh >> 3, head = bh & 7;
        f16* op = og + ((size_t)b * Ss + qbase + q31) * Ee + head * HSs;
        uint2 lo = { pack_rne(o[0], o[1]), pack_rne(o[2], o[3]) };
        uint2 hi = { pack_rne(o[4], o[5]), pack_rne(o[6], o[7]) };
        *(uint2*)(op + 4 * h)     = lo;
        *(uint2*)(op + 8 + 4 * h) = hi;
    }
}

// ---------------------------------------------------------------------------
// Kernel C: output projection. 32-row tiles, grid 512, 4 waves (one channel
// group each). O tile staged via LDS coalesced; Wp f16 (L1-hot); fp32 out.
// ---------------------------------------------------------------------------
__global__ __launch_bounds__(256) void proj_kernel(
    const f16* __restrict__ oh, const f16* __restrict__ wph,
    const float* __restrict__ bp, float* __restrict__ out)
{
    constexpr int LDW = 136;
    __shared__ __align__(16) f16 Os[32 * LDW];    // 8.7 KB
    const int rowbase = blockIdx.x * 32;

    for (int idx = threadIdx.x; idx < 512; idx += 256) {
        const int r = idx >> 4, cp = idx & 15;
        *(f16x8*)&Os[r * LDW + cp * 8] =
            *(const f16x8*)(oh + (size_t)(rowbase + r) * Ee + cp * 8);
    }
    __syncthreads();

    const int wv_ = threadIdx.x >> 6, lane = threadIdx.x & 63;
    const int h = lane >> 5, n31 = lane & 31;

    f16x8 A[8];
#pragma unroll
    for (int t = 0; t < 8; ++t)
        A[t] = *(const f16x8*)&Os[n31 * LDW + 16 * t + 8 * h];

    const int e = wv_ * 32 + n31;
    const f16* wr = wph + (size_t)e * Ee + 8 * h;
    f32x16 acc = {};
#pragma unroll
    for (int t = 0; t < 8; ++t)
        acc = __builtin_amdgcn_mfma_f32_32x32x16_f16(A[t], *(const f16x8*)(wr + 16 * t), acc, 0, 0, 0);

    const float bias = bp[e];
#pragma unroll
    for (int r = 0; r < 16; ++r) {
        const int R = rowbase + (r & 3) + 8 * (r >> 2) + 4 * h;
        out[(size_t)R * Ee + e] = acc[r] + bias;
    }
}

// ---------------------------------------------------------------------------
extern "C" void kernel_launch(void* const* d_in, const int* in_sizes, int n_in,
                              void* d_out, int out_size, void* d_ws, size_t ws_size,
                              hipStream_t stream)
{
    const float* x  = (const float*)d_in[0];
    const float* Wk = (const float*)d_in[1];
    const float* Wq = (const float*)d_in[2];
    const float* Wv = (const float*)d_in[3];
    const float* Wp = (const float*)d_in[4];
    const float* bp = (const float*)d_in[5];
    float* out = (float*)d_out;

    f16* ws = (f16*)d_ws;
    f16* qh = ws;                            // 2M halves
    f16* kh = ws + (size_t)QKVSZ;            // 2M
    f16* vh = ws + (size_t)2 * QKVSZ;        // 4M (A-frag order + pad rows)
    f16* oh = ws + (size_t)4 * QKVSZ;        // 2M
    f16* wh = ws + (size_t)5 * QKVSZ;        // 64K: wq|wk|wv|wp

    prep_kernel<<<1088, 256, 0, stream>>>(Wq, Wk, Wv, Wp, wh, vh);
    qkv_kernel<<<Bb * Ss / 32, 256, 0, stream>>>(x, wh, qh, kh, vh);
    attn_kernel<<<Bb * Hh * (Ss / 32), 128, 0, stream>>>(qh, kh, vh, oh);
    proj_kernel<<<Bb * Ss / 32, 256, 0, stream>>>(oh, wh + 49152, bp, out);
}

// Round 15
// 138.477 us; speedup vs baseline: 2.3178x; 1.0274x over previous
//
#include <hip/hip_runtime.h>
#include <hip/hip_bf16.h>

// Problem constants
constexpr int Bb  = 8;
constexpr int Ss  = 2048;
constexpr int Ee  = 128;
constexpr int Hh  = 8;
constexpr int HSs = 16;
constexpr int QKVSZ = Bb * Hh * Ss * HSs;  // 2,097,152 elements per tensor

typedef _Float16 f16;
typedef __attribute__((ext_vector_type(8)))  _Float16 f16x8;   // 8 f16 = 4 VGPRs
typedef __attribute__((ext_vector_type(16))) float f32x16;

constexpr float QSCALE = 5.770780163555854f;  // 4 * log2(e); folded into stored k

// RTZ packed fp32x2 -> fp16x2
__device__ __forceinline__ unsigned pack_rtz(float lo, float hi) {
    union { __fp16 __attribute__((ext_vector_type(2))) h; unsigned u; } c;
    c.h = __builtin_amdgcn_cvt_pkrtz(lo, hi);
    return c.u;
}
// RNE pair pack
__device__ __forceinline__ unsigned pack_rne(float lo, float hi) {
    union { __attribute__((ext_vector_type(2))) _Float16 h; unsigned u; } c;
    c.h[0] = (f16)lo; c.h[1] = (f16)hi;
    return c.u;
}

// ---------------------------------------------------------------------------
// prep: (a) fp32->f16 of all weights into wh=[wq|wk|wv|wp];
//       (b) constant pad rows of the frag-ordered V buffer (m=16 row -> 1.0
//           for the MFMA-l trick, m=17..31 -> 0), fully coalesced.
// ---------------------------------------------------------------------------
__global__ __launch_bounds__(256) void prep_kernel(
    const float* __restrict__ Wq, const float* __restrict__ Wk,
    const float* __restrict__ Wv, const float* __restrict__ Wp,
    f16* __restrict__ wh, f16* __restrict__ vo)
{
    const int idx = blockIdx.x * 256 + threadIdx.x;
    if (idx < 16384) {
        const int i = idx * 4;
        const float* src = (i < 16384) ? (Wq + i)
                         : (i < 32768) ? (Wk + i - 16384)
                         : (i < 49152) ? (Wv + i - 32768) : (Wp + i - 49152);
        float4 v = *(const float4*)src;
        union { f16 h[4]; uint2 u; } c;
        c.h[0] = (f16)v.x; c.h[1] = (f16)v.y; c.h[2] = (f16)v.z; c.h[3] = (f16)v.w;
        *(uint2*)(wh + i) = c.u;
    } else {
        const int p = idx - 16384;                 // 0..262143 pad chunks (16B)
        const int lane32 = p & 31, g = (p >> 5) & 3, it = (p >> 7) & 31, bh = p >> 12;
        const int lanep = 16 + (lane32 & 15) + (lane32 >> 4) * 32;  // 16..31, 48..63
        const unsigned one2 = 0x3C003C00u;         // two f16 1.0
        uint4 val = ((lane32 & 15) == 0) ? (uint4){one2, one2, one2, one2}
                                         : (uint4){0, 0, 0, 0};
        *(uint4*)(vo + (size_t)bh * 65536 + it * 2048 + g * 512 + lanep * 8) = val;
    }
}

// ---------------------------------------------------------------------------
// Kernel A: Q/K/V projection, all 3 mats fused (X staged once). Grid 512 x
// 256 thr. A-frags from LDS; W f16 (L1-hot). v acc routed through an LDS
// transpose -> coalesced uint4 frag-order stores (data rows only; pads are
// pre-written by prep). q/k direct stores, k scaled by QSCALE.
// V frag-order: elem (s,d) -> bh*65536 + (s>>6)*2048 + ((s>>4)&3)*512
//                             + (d + 32*((s>>3)&1))*8 + (s&7)
// 32x32x16 layouts: A[m=lane&31][k=8h+j], B[k=8h+j][n=lane&31],
// C/D[row=(r&3)+8(r>>2)+4h][col=lane&31].
// ---------------------------------------------------------------------------
__global__ __launch_bounds__(256) void qkv_kernel(
    const float* __restrict__ x, const f16* __restrict__ wh,
    f16* __restrict__ qo, f16* __restrict__ ko, f16* __restrict__ vo)
{
    constexpr int LDW = 136;                      // padded row (f16), b128-aligned
    __shared__ __align__(16) f16 Xs[32 * LDW];    // 8.7 KB, reused for v transpose

    const int rowbase = blockIdx.x * 32;

    // stage X tile (32 x 128) fp32 -> f16, coalesced float4 reads
    for (int idx = threadIdx.x; idx < 32 * 32; idx += 256) {
        const int r = idx >> 5, cp = idx & 31;
        float4 v = *(const float4*)(x + (size_t)(rowbase + r) * Ee + cp * 4);
        union { f16 h[4]; uint2 u; } c;
        c.h[0] = (f16)v.x; c.h[1] = (f16)v.y; c.h[2] = (f16)v.z; c.h[3] = (f16)v.w;
        *(uint2*)&Xs[r * LDW + cp * 4] = c.u;
    }
    __syncthreads();

    const int wv_ = threadIdx.x >> 6, lane = threadIdx.x & 63;
    const int h = lane >> 5, n31 = lane & 31;

    f16x8 A[8];
#pragma unroll
    for (int t = 0; t < 8; ++t)
        A[t] = *(const f16x8*)&Xs[n31 * LDW + 16 * t + 8 * h];
    __syncthreads();                              // all A-frag reads done

    const int c = wv_ * 32 + n31;                 // channel 0..127 = head*16+d
    const int b = rowbase >> 11;
    const int s0 = rowbase & 2047;
    const int head = c >> 4, d = c & 15;
    const int bh = b * Hh + head;

    // --- V first: MFMA then transpose via Xs ---
    {
        const f16* wr = wh + 2 * 16384 + (size_t)c * Ee + 8 * h;
        f32x16 acc = {};
#pragma unroll
        for (int t = 0; t < 8; ++t)
            acc = __builtin_amdgcn_mfma_f32_32x32x16_f16(A[t], *(const f16x8*)(wr + 16 * t), acc, 0, 0, 0);
#pragma unroll
        for (int r = 0; r < 16; ++r) {
            const int row = (r & 3) + 8 * (r >> 2) + 4 * h;
            Xs[row * LDW + c] = (f16)acc[r];
        }
    }

    // --- Q and K while the transpose settles ---
#pragma unroll
    for (int mat = 0; mat < 2; ++mat) {
        const f16* wr = wh + mat * 16384 + (size_t)c * Ee + 8 * h;
        f32x16 acc = {};
#pragma unroll
        for (int t = 0; t < 8; ++t)
            acc = __builtin_amdgcn_mfma_f32_32x32x16_f16(A[t], *(const f16x8*)(wr + 16 * t), acc, 0, 0, 0);
        f16* dst = (mat == 0) ? qo : ko;
        const float scale = (mat == 1) ? QSCALE : 1.f;
#pragma unroll
        for (int r = 0; r < 16; ++r) {
            const int s = s0 + (r & 3) + 8 * (r >> 2) + 4 * h;
            dst[((size_t)bh * Ss + s) * HSs + d] = (f16)(acc[r] * scale);
        }
    }
    __syncthreads();                              // v transpose complete

    // coalesced frag-order v stores (512 uint4 per block, data rows only)
    const int it = s0 >> 6, g0 = (s0 >> 4) & 3;
    for (int p = threadIdx.x; p < 512; p += 256) {
        const int gl = p >> 8, hd = (p >> 5) & 7, dd = (p >> 1) & 15, eh = p & 1;
        union { f16 hv[8]; uint4 u; } pkt;
#pragma unroll
        for (int j = 0; j < 8; ++j)
            pkt.hv[j] = Xs[(gl * 16 + eh * 8 + j) * LDW + hd * 16 + dd];
        *(uint4*)(vo + (size_t)(b * Hh + hd) * 65536 + it * 2048
                  + (g0 + gl) * 512 + (dd + 32 * eh) * 8) = pkt.u;
    }
}

// ---------------------------------------------------------------------------
// Kernel B: FUSED flash attention + output projection.
// Block = 8 waves (512 thr) = one (b, 32-query tile); wave w = head w,
// streaming ALL 2048 keys with R12's no-LDS loop (direct 16B/lane global
// operands, V pre-swizzled with ones-row -> l in acc[8], register prefetch).
// Epilogue: normalized O (f16) -> LDS tile [32 q][128 ch], one barrier,
// waves 0..3 run the proj MFMA chain (Wp f16, L1-hot) + bias -> fp32 out.
// XCD pinning: b = blk&7 -> all 64 q-blocks of a batch share one XCD's L2.
// __launch_bounds__(512, 2): VGPR cap 256 >> ~70 needed — no spill.
// ---------------------------------------------------------------------------
__device__ __forceinline__ void cb_exchange(const unsigned* pw, int h,
                                            f16x8& Blo, f16x8& Bhi) {
    unsigned exa = (unsigned)__shfl_xor((int)(h ? pw[0] : pw[2]), 32, 64);
    unsigned exb = (unsigned)__shfl_xor((int)(h ? pw[1] : pw[3]), 32, 64);
    unsigned exc = (unsigned)__shfl_xor((int)(h ? pw[4] : pw[6]), 32, 64);
    unsigned exd = (unsigned)__shfl_xor((int)(h ? pw[5] : pw[7]), 32, 64);
    union { unsigned u[4]; f16x8 v; } B1, B2;
    if (h == 0) {
        B1.u[0] = pw[0]; B1.u[1] = pw[1]; B1.u[2] = exa; B1.u[3] = exb;
        B2.u[0] = pw[4]; B2.u[1] = pw[5]; B2.u[2] = exc; B2.u[3] = exd;
    } else {
        B1.u[0] = exa; B1.u[1] = exb; B1.u[2] = pw[2]; B1.u[3] = pw[3];
        B2.u[0] = exc; B2.u[1] = exd; B2.u[2] = pw[6]; B2.u[3] = pw[7];
    }
    Blo = B1.v; Bhi = B2.v;
}

__global__ __launch_bounds__(512, 2) void attn_kernel(
    const f16* __restrict__ qg, const f16* __restrict__ kg,
    const f16* __restrict__ vg, const f16* __restrict__ wph,
    const float* __restrict__ bp, float* __restrict__ out)
{
    constexpr int LDW = 136;
    __shared__ __align__(16) f16 Os[32 * LDW];     // O tile [q][ch], 8.7 KB

    const int blk  = blockIdx.x;                   // 512
    const int b    = blk & 7;                      // XCD-pinned batch
    const int qblk = blk >> 3;                     // 0..63
    const int wv_  = threadIdx.x >> 6;             // head 0..7
    const int lane = threadIdx.x & 63;
    const int h    = lane >> 5;
    const int q31  = lane & 31;
    const int qbase = qblk * 32;
    const int bh   = b * Hh + wv_;

    // Q B-frag (QSCALE folded into k)
    const f16x8 qf = *(const f16x8*)(qg + ((size_t)bh * Ss + qbase + q31) * HSs + 8 * h);

    // per-lane streaming pointers (16B/lane contiguous, coalesced per wave)
    const f16* pk = kg + (size_t)bh * Ss * HSs + q31 * 16 + 8 * h;
    const f16* pv = vg + (size_t)bh * 65536 + lane * 8;

    f16x8 ka0 = *(const f16x8*)pk;
    f16x8 ka1 = *(const f16x8*)(pk + 512);
    f16x8 va0 = *(const f16x8*)(pv);
    f16x8 va1 = *(const f16x8*)(pv + 512);
    f16x8 va2 = *(const f16x8*)(pv + 1024);
    f16x8 va3 = *(const f16x8*)(pv + 1536);

    f32x16 acc = {};
    const f32x16 z16 = {};
    float m = -1e30f;

    for (int it = 0; it < Ss / 64; ++it) {
        f16x8 nk0, nk1, nv0, nv1, nv2, nv3;
        if (it < Ss / 64 - 1) {
            pk += 1024; pv += 2048;
            nk0 = *(const f16x8*)pk;
            nk1 = *(const f16x8*)(pk + 512);
            nv0 = *(const f16x8*)(pv);
            nv1 = *(const f16x8*)(pv + 512);
            nv2 = *(const f16x8*)(pv + 1024);
            nv3 = *(const f16x8*)(pv + 1536);
        }

        // S^T = K x Q^T for key groups 0..31, 32..63
        f32x16 st0 = __builtin_amdgcn_mfma_f32_32x32x16_f16(ka0, qf, z16, 0, 0, 0);
        f32x16 st1 = __builtin_amdgcn_mfma_f32_32x32x16_f16(ka1, qf, z16, 0, 0, 0);

        // balanced max tree over 32 in-lane values + one xor32
        float t0[8];
#pragma unroll
        for (int t = 0; t < 8; ++t)
            t0[t] = fmaxf(fmaxf(st0[t], st0[t + 8]), fmaxf(st1[t], st1[t + 8]));
#pragma unroll
        for (int t = 0; t < 4; ++t) t0[t] = fmaxf(t0[t], t0[t + 4]);
        float mx = fmaxf(fmaxf(t0[0], t0[1]), fmaxf(t0[2], t0[3]));
        mx = fmaxf(mx, __shfl_xor(mx, 32, 64));
        const float mnew = fmaxf(m, mx);
        const float corr = __builtin_amdgcn_exp2f(m - mnew);
#pragma unroll
        for (int r = 0; r < 9; ++r) acc[r] *= corr;   // d<16 regs + l in acc[8]
        m = mnew;

#pragma unroll
        for (int t = 0; t < 16; ++t) st0[t] = __builtin_amdgcn_exp2f(st0[t] - mnew);
#pragma unroll
        for (int t = 0; t < 16; ++t) st1[t] = __builtin_amdgcn_exp2f(st1[t] - mnew);
        unsigned pw0[8], pw1[8];
#pragma unroll
        for (int r = 0; r < 8; ++r) pw0[r] = pack_rtz(st0[2 * r], st0[2 * r + 1]);
#pragma unroll
        for (int r = 0; r < 8; ++r) pw1[r] = pack_rtz(st1[2 * r], st1[2 * r + 1]);
        f16x8 B1, B2, B3, B4;
        cb_exchange(pw0, h, B1, B2);
        cb_exchange(pw1, h, B3, B4);

        // O^T += V'^T x P^T (ones-row at m=16 accumulates l into acc[8])
        acc = __builtin_amdgcn_mfma_f32_32x32x16_f16(va0, B1, acc, 0, 0, 0);
        acc = __builtin_amdgcn_mfma_f32_32x32x16_f16(va1, B2, acc, 0, 0, 0);
        acc = __builtin_amdgcn_mfma_f32_32x32x16_f16(va2, B3, acc, 0, 0, 0);
        acc = __builtin_amdgcn_mfma_f32_32x32x16_f16(va3, B4, acc, 0, 0, 0);

        ka0 = nk0; ka1 = nk1;
        va0 = nv0; va1 = nv1; va2 = nv2; va3 = nv3;
    }

    // l from ones-row (acc[8] of h=0 half); normalize; publish O tile to LDS
    const float l = acc[8] + __shfl_xor(acc[8], 32, 64);
    const float inv = 1.f / l;
    {
        unsigned w0 = pack_rne(acc[0] * inv, acc[1] * inv);
        unsigned w1 = pack_rne(acc[2] * inv, acc[3] * inv);
        unsigned w2 = pack_rne(acc[4] * inv, acc[5] * inv);
        unsigned w3 = pack_rne(acc[6] * inv, acc[7] * inv);
        f16* od = &Os[q31 * LDW + wv_ * HSs];
        *(uint2*)(od + 4 * h)     = (uint2){w0, w1};
        *(uint2*)(od + 8 + 4 * h) = (uint2){w2, w3};
    }
    __syncthreads();

    // proj epilogue on waves 0..3: out[s, e] = O[s,:] . Wp[e,:] + bp[e]
    if (wv_ < 4) {
        f16x8 A[8];
#pragma unroll
        for (int t = 0; t < 8; ++t)
            A[t] = *(const f16x8*)&Os[q31 * LDW + 16 * t + 8 * h];

        const int e = wv_ * 32 + q31;
        const f16* wr = wph + (size_t)e * Ee + 8 * h;
        f32x16 pacc = {};
#pragma unroll
        for (int t = 0; t < 8; ++t)
            pacc = __builtin_amdgcn_mfma_f32_32x32x16_f16(A[t], *(const f16x8*)(wr + 16 * t), pacc, 0, 0, 0);

        const float bias = bp[e];
#pragma unroll
        for (int r = 0; r < 16; ++r) {
            const int R = qbase + (r & 3) + 8 * (r >> 2) + 4 * h;
            out[((size_t)b * Ss + R) * Ee + e] = pacc[r] + bias;
        }
    }
}

// ---------------------------------------------------------------------------
extern "C" void kernel_launch(void* const* d_in, const int* in_sizes, int n_in,
                              void* d_out, int out_size, void* d_ws, size_t ws_size,
                              hipStream_t stream)
{
    const float* x  = (const float*)d_in[0];
    const float* Wk = (const float*)d_in[1];
    const float* Wq = (const float*)d_in[2];
    const float* Wv = (const float*)d_in[3];
    const float* Wp = (const float*)d_in[4];
    const float* bp = (const float*)d_in[5];
    float* out = (float*)d_out;

    f16* ws = (f16*)d_ws;
    f16* qh = ws;                            // 2M halves
    f16* kh = ws + (size_t)QKVSZ;            // 2M
    f16* vh = ws + (size_t)2 * QKVSZ;        // 4M (A-frag order + pad rows)
    f16* wh = ws + (size_t)4 * QKVSZ;        // 64K: wq|wk|wv|wp

    prep_kernel<<<1088, 256, 0, stream>>>(Wq, Wk, Wv, Wp, wh, vh);
    qkv_kernel<<<Bb * Ss / 32, 256, 0, stream>>>(x, wh, qh, kh, vh);
    attn_kernel<<<Bb * (Ss / 32), 512, 0, stream>>>(qh, kh, vh, wh + 49152, bp, out);
}